// Round 14
// baseline (557.702 us; speedup 1.0000x reference)
//
#include <hip/hip_runtime.h>
#include <math.h>

#define H 256
#define EPS 1e-5f

typedef __attribute__((ext_vector_type(8))) short bf16x8;
typedef __attribute__((ext_vector_type(4))) float f32x4;

__device__ inline ushort f2b(float f) {
  union { float f; unsigned u; } v; v.f = f;
  unsigned r = v.u + 0x7FFF + ((v.u >> 16) & 1);
  return (ushort)(r >> 16);
}
__device__ inline float b2f(ushort u) {
  union { unsigned u; float f; } v; v.u = ((unsigned)u) << 16;
  return v.f;
}

// ---------- index dtype detection & conversion (+fused degree count) ----------
__global__ void detect_i64_k(const int* __restrict__ w, int* __restrict__ flag) {
  if (threadIdx.x == 0 && blockIdx.x == 0) {
    int all0 = 1;
    for (int k = 0; k < 64; k++) if (w[2*k+1] != 0) { all0 = 0; break; }
    *flag = all0;
  }
}

__global__ void convert_idx_k(const void* __restrict__ raw, const int* __restrict__ flag,
                              int* __restrict__ out, int n,
                              int* __restrict__ cnt, int countFrom) {
  int i = blockIdx.x*256 + threadIdx.x;
  if (i >= n) return;
  int v;
  if (*flag) v = (int)((const long long*)raw)[i];
  else       v = ((const int*)raw)[i];
  out[i] = v;
  if (cnt && i >= countFrom) atomicAdd(&cnt[v], 1);
}

// ---------- hierarchical exclusive scan (+fused dinv) ----------
__global__ void scan1_k(const int* __restrict__ cnt, int* __restrict__ rowptr,
                        int* __restrict__ bsum, float* __restrict__ dinv, int N_) {
  __shared__ int sh[256];
  int t = threadIdx.x;
  int i0 = blockIdx.x*1024 + t*4;
  int v0=0,v1=0,v2=0,v3=0;
  if (i0+0 < N_) v0 = cnt[i0+0];
  if (i0+1 < N_) v1 = cnt[i0+1];
  if (i0+2 < N_) v2 = cnt[i0+2];
  if (i0+3 < N_) v3 = cnt[i0+3];
  if (i0+0 < N_) dinv[i0+0] = rsqrtf((float)v0 + 1.0f);
  if (i0+1 < N_) dinv[i0+1] = rsqrtf((float)v1 + 1.0f);
  if (i0+2 < N_) dinv[i0+2] = rsqrtf((float)v2 + 1.0f);
  if (i0+3 < N_) dinv[i0+3] = rsqrtf((float)v3 + 1.0f);
  sh[t] = v0+v1+v2+v3;
  __syncthreads();
  for (int off = 1; off < 256; off <<= 1) {
    int x = (t >= off) ? sh[t-off] : 0;
    __syncthreads();
    sh[t] += x;
    __syncthreads();
  }
  int excl = (t == 0) ? 0 : sh[t-1];
  if (i0+0 < N_) rowptr[i0+0] = excl;
  if (i0+1 < N_) rowptr[i0+1] = excl+v0;
  if (i0+2 < N_) rowptr[i0+2] = excl+v0+v1;
  if (i0+3 < N_) rowptr[i0+3] = excl+v0+v1+v2;
  if (t == 255) bsum[blockIdx.x] = sh[255];
}

__global__ void scan2_k(int* __restrict__ bsum, int* __restrict__ rowptr,
                        int nb, int N_) {
  int lane = threadIdx.x; // 64 threads
  int carry = 0;
  for (int base = 0; base < nb; base += 64) {
    int i = base + lane;
    int orig = (i < nb) ? bsum[i] : 0;
    int v = orig;
    for (int off = 1; off < 64; off <<= 1) {
      int u = __shfl_up(v, off);
      if (lane >= off) v += u;
    }
    if (i < nb) bsum[i] = carry + v - orig; // exclusive
    carry += __shfl(v, 63);
  }
  if (lane == 0) rowptr[N_] = carry;
}

__global__ void scan3_k(int* __restrict__ rowptr, const int* __restrict__ bsum, int N_) {
  int off = bsum[blockIdx.x];
  int i = blockIdx.x*1024 + threadIdx.x*4;
#pragma unroll
  for (int k = 0; k < 4; k++) if (i+k < N_) rowptr[i+k] += off;
}

__global__ void fill_csr_k(const int* __restrict__ row, const int* __restrict__ col,
                           const int* __restrict__ rowptr, int* __restrict__ fill,
                           int* __restrict__ src, int E_) {
  int e = blockIdx.x*256 + threadIdx.x;
  if (e < E_) {
    int c = col[e];
    int p = rowptr[c] + atomicAdd(&fill[c], 1);
    src[p] = row[e];
  }
}

__global__ void graph_starts_k(const int* __restrict__ batch, int* __restrict__ gstart,
                               int N_, int G_) {
  int g = blockIdx.x*256 + threadIdx.x;
  if (g > G_) return;
  int lo = 0, hi = N_;
  while (lo < hi) { int m = (lo+hi) >> 1; if (batch[m] < g) lo = m+1; else hi = m; }
  gstart[g] = lo;
}

// ---------- xs[r][f] = bf16(dinv[r] * x[r][f]) ----------
__global__ void xs_k(const float* __restrict__ x, const float* __restrict__ dinv,
                     ushort* __restrict__ xs, int n4, int F_) {
  int i = blockIdx.x*256 + threadIdx.x;
  if (i >= n4) return;
  int row = (i << 2) / F_;
  float dv = dinv[row];
  float4 v = ((const float4*)x)[i];
  ushort4 o;
  o.x = f2b(v.x*dv); o.y = f2b(v.y*dv); o.z = f2b(v.z*dv); o.w = f2b(v.w*dv);
  ((ushort4*)xs)[i] = o;
}

// ---------- all three weight transposes in one kernel ----------
__global__ void wt3_k(const float* __restrict__ W0, const float* __restrict__ W1,
                      const float* __restrict__ W2, ushort* __restrict__ Wt0,
                      ushort* __restrict__ Wt1, ushort* __restrict__ Wt2,
                      int ksh0, int n0) {
  int idx = blockIdx.x*256 + threadIdx.x;
  if (idx < n0) {
    int n = idx >> ksh0, k = idx & ((1 << ksh0) - 1);
    Wt0[idx] = f2b(W0[(size_t)k*H + n]);
  } else if (idx < n0 + H*H) {
    int j = idx - n0;
    int n = j >> 8, k = j & 255;
    Wt1[j] = f2b(W1[(size_t)k*H + n]);
  } else if (idx < n0 + 2*H*H) {
    int j = idx - n0 - H*H;
    int n = j >> 8, k = j & 255;
    Wt2[j] = f2b(W2[(size_t)k*H + n]);
  }
}

// ---------- layer-0 aggregation on F channels: z = bf16(Â x) ----------
__global__ __launch_bounds__(1024) void aggregate0_k(
    const ushort* __restrict__ xs, const int* __restrict__ src,
    const int* __restrict__ rowptr, const float* __restrict__ dinv,
    ushort* __restrict__ z, int N_, int F_) {
  int t = threadIdx.x;
  int lane = t & 63, wv = t >> 6;
  int ch = lane * 2;
  for (int c = blockIdx.x*16 + wv; c < N_; c += gridDim.x*16) {
    float di = dinv[c];
    ushort2 sv = *(const ushort2*)(xs + (size_t)c*F_ + ch);
    float a0 = b2f(sv.x), b0 = b2f(sv.y);
    float a1=0.f,b1=0.f,a2=0.f,b2=0.f,a3=0.f,b3=0.f;
    int s = rowptr[c], e = rowptr[c+1];
    int j = s;
    for (; j + 8 <= e; j += 8) {
      int r0 = src[j],   r1 = src[j+1], r2 = src[j+2], r3 = src[j+3];
      int r4 = src[j+4], r5 = src[j+5], r6 = src[j+6], r7 = src[j+7];
      ushort2 v0 = *(const ushort2*)(xs + (size_t)r0*F_ + ch);
      ushort2 v1 = *(const ushort2*)(xs + (size_t)r1*F_ + ch);
      ushort2 v2 = *(const ushort2*)(xs + (size_t)r2*F_ + ch);
      ushort2 v3 = *(const ushort2*)(xs + (size_t)r3*F_ + ch);
      ushort2 v4 = *(const ushort2*)(xs + (size_t)r4*F_ + ch);
      ushort2 v5 = *(const ushort2*)(xs + (size_t)r5*F_ + ch);
      ushort2 v6 = *(const ushort2*)(xs + (size_t)r6*F_ + ch);
      ushort2 v7 = *(const ushort2*)(xs + (size_t)r7*F_ + ch);
      a0 += b2f(v0.x); b0 += b2f(v0.y);
      a1 += b2f(v1.x); b1 += b2f(v1.y);
      a2 += b2f(v2.x); b2 += b2f(v2.y);
      a3 += b2f(v3.x); b3 += b2f(v3.y);
      a0 += b2f(v4.x); b0 += b2f(v4.y);
      a1 += b2f(v5.x); b1 += b2f(v5.y);
      a2 += b2f(v6.x); b2 += b2f(v6.y);
      a3 += b2f(v7.x); b3 += b2f(v7.y);
    }
    for (; j + 4 <= e; j += 4) {
      int r0 = src[j], r1 = src[j+1], r2 = src[j+2], r3 = src[j+3];
      ushort2 v0 = *(const ushort2*)(xs + (size_t)r0*F_ + ch);
      ushort2 v1 = *(const ushort2*)(xs + (size_t)r1*F_ + ch);
      ushort2 v2 = *(const ushort2*)(xs + (size_t)r2*F_ + ch);
      ushort2 v3 = *(const ushort2*)(xs + (size_t)r3*F_ + ch);
      a0 += b2f(v0.x); b0 += b2f(v0.y);
      a1 += b2f(v1.x); b1 += b2f(v1.y);
      a2 += b2f(v2.x); b2 += b2f(v2.y);
      a3 += b2f(v3.x); b3 += b2f(v3.y);
    }
    for (; j < e; j++) {
      int r = src[j];
      ushort2 v = *(const ushort2*)(xs + (size_t)r*F_ + ch);
      a0 += b2f(v.x); b0 += b2f(v.y);
    }
    float sa = (a0+a1)+(a2+a3);
    float sb = (b0+b1)+(b2+b3);
    ushort2 o; o.x = f2b(sa*di); o.y = f2b(sb*di);
    *(ushort2*)(z + (size_t)c*F_ + ch) = o;
  }
}

// ---------- GEMM with LDS-staged A tile, deep-pipelined (R12 version) ----------
template<int K, int MODE, int FUSE, int RES>
__global__ __launch_bounds__(256) void gemm_mfma_k(
    const ushort* __restrict__ A, const ushort* __restrict__ Wt,
    const float* __restrict__ dinv, const float* __restrict__ bias,
    const float* __restrict__ stats, const float* __restrict__ g,
    const float* __restrict__ beta, ushort* __restrict__ hb,
    ushort* __restrict__ y, ushort* __restrict__ aggb_out,
    float* __restrict__ statsout, int N_, float invN) {
  __shared__ ushort At[64*256];
  __shared__ float scsh[2*H];
  __shared__ float ls[2*H];
  int t = threadIdx.x;
  int lane = t & 63, w = t >> 6;
  int r0 = blockIdx.x * 64;
  int c0 = w * 64;
  int lr = lane & 15, lk = (lane >> 4) * 8;
  const int ROWB = K*2;

  if (FUSE) {
    float mu  = stats[t]*invN;
    float var = stats[H+t]*invN - mu*mu;
    float sc  = g[t]*rsqrtf(var+EPS);
    scsh[t] = sc; scsh[H+t] = beta[t] - mu*sc;
    __syncthreads();
  }
  constexpr int C4PR = K/4;
  constexpr int ITER = 64*C4PR/256;
#pragma unroll
  for (int it = 0; it < ITER; it++) {
    int idx = it*256 + t;
    int row = idx / C4PR;
    int c4 = (idx % C4PR) * 4;
    int grow = r0 + row;
    int gr = (grow < N_) ? grow : (N_-1);
    ushort4 av = *(const ushort4*)(A + (size_t)gr*K + c4);
    ushort4 o;
    if (FUSE) {
      float x0 = fmaxf(fmaf(b2f(av.x), scsh[c4+0], scsh[H+c4+0]), 0.f);
      float x1 = fmaxf(fmaf(b2f(av.y), scsh[c4+1], scsh[H+c4+1]), 0.f);
      float x2 = fmaxf(fmaf(b2f(av.z), scsh[c4+2], scsh[H+c4+2]), 0.f);
      float x3 = fmaxf(fmaf(b2f(av.w), scsh[c4+3], scsh[H+c4+3]), 0.f);
      if (RES) {
        ushort4 hv = *(const ushort4*)(hb + (size_t)gr*K + c4);
        x0 += b2f(hv.x); x1 += b2f(hv.y); x2 += b2f(hv.z); x3 += b2f(hv.w);
      }
      o.x = f2b(x0); o.y = f2b(x1); o.z = f2b(x2); o.w = f2b(x3);
      if (grow < N_) *(ushort4*)(hb + (size_t)grow*K + c4) = o;
    } else {
      o = av;
    }
    int byte = row*ROWB + ((c4*2) ^ ((row&7)<<4));
    *(ushort4*)((char*)At + byte) = o;
  }
  __syncthreads();

  f32x4 acc[4][4];
#pragma unroll
  for (int m = 0; m < 4; m++)
#pragma unroll
    for (int n = 0; n < 4; n++) acc[m][n] = (f32x4)0.f;

  const ushort* Wp[4];
#pragma unroll
  for (int n = 0; n < 4; n++) Wp[n] = Wt + (size_t)(c0 + n*16 + lr)*K + lk;

  const int NSTEP = K / 32;
  bf16x8 w0[4], w1[4], w2[4], a_cur[4], a_nxt[4];
#pragma unroll
  for (int n = 0; n < 4; n++) w0[n] = *(const bf16x8*)(Wp[n]);
#pragma unroll
  for (int n = 0; n < 4; n++) w1[n] = *(const bf16x8*)(Wp[n] + (NSTEP > 1 ? 32 : 0));
#pragma unroll
  for (int m = 0; m < 4; m++) {
    int row = m*16 + lr;
    int byte = row*ROWB + ((lk*2) ^ ((row&7)<<4));
    a_cur[m] = *(const bf16x8*)((const char*)At + byte);
  }

#pragma unroll
  for (int s = 0; s < NSTEP; s++) {
    if (s + 2 < NSTEP) {
      int k0 = (s + 2) * 32;
#pragma unroll
      for (int n = 0; n < 4; n++) w2[n] = *(const bf16x8*)(Wp[n] + k0);
    }
    if (s + 1 < NSTEP) {
#pragma unroll
      for (int m = 0; m < 4; m++) {
        int row = m*16 + lr;
        int byte = row*ROWB + ((((lk + (s+1)*32)*2)) ^ ((row&7)<<4));
        a_nxt[m] = *(const bf16x8*)((const char*)At + byte);
      }
    }
#pragma unroll
    for (int m = 0; m < 4; m++)
#pragma unroll
      for (int n = 0; n < 4; n++)
        acc[m][n] = __builtin_amdgcn_mfma_f32_16x16x32_bf16(a_cur[m], w0[n], acc[m][n], 0, 0, 0);
    if (s + 1 < NSTEP) {
#pragma unroll
      for (int n = 0; n < 4; n++) { w0[n] = w1[n]; }
#pragma unroll
      for (int m = 0; m < 4; m++) a_cur[m] = a_nxt[m];
    }
    if (s + 2 < NSTEP) {
#pragma unroll
      for (int n = 0; n < 4; n++) w1[n] = w2[n];
    }
  }

  int lrow = (lane >> 4) * 4;
  int lcol = lane & 15;

  if (MODE == 0) {
#pragma unroll
    for (int m = 0; m < 4; m++) {
#pragma unroll
      for (int r = 0; r < 4; r++) {
        int row = r0 + m*16 + lrow + r;
        if (row < N_) {
          float dv = dinv[row];
#pragma unroll
          for (int n = 0; n < 4; n++)
            y[(size_t)row*H + c0 + n*16 + lcol] = f2b(acc[m][n][r] * dv);
        }
      }
    }
  } else {
    ls[t] = 0.f; ls[t + H] = 0.f;
    __syncthreads();
    float bvn[4];
#pragma unroll
    for (int n = 0; n < 4; n++) bvn[n] = bias[c0 + n*16 + lcol];
    float sn[4] = {0.f,0.f,0.f,0.f}, qn[4] = {0.f,0.f,0.f,0.f};
#pragma unroll
    for (int m = 0; m < 4; m++) {
#pragma unroll
      for (int r = 0; r < 4; r++) {
        int row = r0 + m*16 + lrow + r;
        if (row < N_) {
#pragma unroll
          for (int n = 0; n < 4; n++) {
            float v = acc[m][n][r] + bvn[n];
            aggb_out[(size_t)row*H + c0 + n*16 + lcol] = f2b(v);
            sn[n] += v; qn[n] = fmaf(v, v, qn[n]);
          }
        }
      }
    }
#pragma unroll
    for (int n = 0; n < 4; n++) {
      atomicAdd(&ls[c0 + n*16 + lcol], sn[n]);
      atomicAdd(&ls[H + c0 + n*16 + lcol], qn[n]);
    }
    __syncthreads();
    atomicAdd(&statsout[t], ls[t]);
    atomicAdd(&statsout[H + t], ls[H + t]);
  }
}

// ---------- aggregation + fused BN stats (layers 1,2) ----------
// 512-thread blocks (8 waves) x 2048 blocks: finer packing granularity ->
// higher occupancy than 1024-thread blocks (2-block/CU quantization).
__global__ __launch_bounds__(512) void aggregate_k(
    const ushort* __restrict__ y, const int* __restrict__ src,
    const int* __restrict__ rowptr, const float* __restrict__ dinv,
    const float* __restrict__ b, ushort* __restrict__ aggb,
    float* __restrict__ stats, int N_) {
  __shared__ float ls[2*H];
  int t = threadIdx.x;
  ls[t] = 0.f;
  __syncthreads();

  int lane = t & 63, wv = t >> 6;   // wv in [0,8)
  int ch = lane * 4;
  float4 bv = *(const float4*)(b + ch);

  float s0=0.f, s1=0.f, s2=0.f, s3=0.f;
  float q0=0.f, q1=0.f, q2=0.f, q3=0.f;

  for (int c = blockIdx.x*8 + wv; c < N_; c += gridDim.x*8) {
    float di = dinv[c];
    ushort4 sv = *(const ushort4*)(y + (size_t)c*H + ch);
    float a0x = b2f(sv.x), a0y = b2f(sv.y), a0z = b2f(sv.z), a0w = b2f(sv.w);
    float a1x=0.f,a1y=0.f,a1z=0.f,a1w=0.f;
    float a2x=0.f,a2y=0.f,a2z=0.f,a2w=0.f;
    float a3x=0.f,a3y=0.f,a3z=0.f,a3w=0.f;
    int s = rowptr[c], e = rowptr[c+1];
    int j = s;
    for (; j + 8 <= e; j += 8) {
      int r0 = src[j],   r1 = src[j+1], r2 = src[j+2], r3 = src[j+3];
      int r4 = src[j+4], r5 = src[j+5], r6 = src[j+6], r7 = src[j+7];
      ushort4 v0 = *(const ushort4*)(y + (size_t)r0*H + ch);
      ushort4 v1 = *(const ushort4*)(y + (size_t)r1*H + ch);
      ushort4 v2 = *(const ushort4*)(y + (size_t)r2*H + ch);
      ushort4 v3 = *(const ushort4*)(y + (size_t)r3*H + ch);
      ushort4 v4 = *(const ushort4*)(y + (size_t)r4*H + ch);
      ushort4 v5 = *(const ushort4*)(y + (size_t)r5*H + ch);
      ushort4 v6 = *(const ushort4*)(y + (size_t)r6*H + ch);
      ushort4 v7 = *(const ushort4*)(y + (size_t)r7*H + ch);
      a0x += b2f(v0.x); a0y += b2f(v0.y); a0z += b2f(v0.z); a0w += b2f(v0.w);
      a1x += b2f(v1.x); a1y += b2f(v1.y); a1z += b2f(v1.z); a1w += b2f(v1.w);
      a2x += b2f(v2.x); a2y += b2f(v2.y); a2z += b2f(v2.z); a2w += b2f(v2.w);
      a3x += b2f(v3.x); a3y += b2f(v3.y); a3z += b2f(v3.z); a3w += b2f(v3.w);
      a0x += b2f(v4.x); a0y += b2f(v4.y); a0z += b2f(v4.z); a0w += b2f(v4.w);
      a1x += b2f(v5.x); a1y += b2f(v5.y); a1z += b2f(v5.z); a1w += b2f(v5.w);
      a2x += b2f(v6.x); a2y += b2f(v6.y); a2z += b2f(v6.z); a2w += b2f(v6.w);
      a3x += b2f(v7.x); a3y += b2f(v7.y); a3z += b2f(v7.z); a3w += b2f(v7.w);
    }
    for (; j + 4 <= e; j += 4) {
      int r0 = src[j], r1 = src[j+1], r2 = src[j+2], r3 = src[j+3];
      ushort4 v0 = *(const ushort4*)(y + (size_t)r0*H + ch);
      ushort4 v1 = *(const ushort4*)(y + (size_t)r1*H + ch);
      ushort4 v2 = *(const ushort4*)(y + (size_t)r2*H + ch);
      ushort4 v3 = *(const ushort4*)(y + (size_t)r3*H + ch);
      a0x += b2f(v0.x); a0y += b2f(v0.y); a0z += b2f(v0.z); a0w += b2f(v0.w);
      a1x += b2f(v1.x); a1y += b2f(v1.y); a1z += b2f(v1.z); a1w += b2f(v1.w);
      a2x += b2f(v2.x); a2y += b2f(v2.y); a2z += b2f(v2.z); a2w += b2f(v2.w);
      a3x += b2f(v3.x); a3y += b2f(v3.y); a3z += b2f(v3.z); a3w += b2f(v3.w);
    }
    for (; j < e; j++) {
      int r = src[j];
      ushort4 v = *(const ushort4*)(y + (size_t)r*H + ch);
      a0x += b2f(v.x); a0y += b2f(v.y); a0z += b2f(v.z); a0w += b2f(v.w);
    }
    float ax = (a0x + a1x) + (a2x + a3x);
    float ay = (a0y + a1y) + (a2y + a3y);
    float az = (a0z + a1z) + (a2z + a3z);
    float aw = (a0w + a1w) + (a2w + a3w);
    float ox = fmaf(ax, di, bv.x);
    float oy = fmaf(ay, di, bv.y);
    float oz = fmaf(az, di, bv.z);
    float ow = fmaf(aw, di, bv.w);
    ushort4 ob; ob.x = f2b(ox); ob.y = f2b(oy); ob.z = f2b(oz); ob.w = f2b(ow);
    *(ushort4*)(aggb + (size_t)c*H + ch) = ob;
    s0 += ox; q0 = fmaf(ox, ox, q0);
    s1 += oy; q1 = fmaf(oy, oy, q1);
    s2 += oz; q2 = fmaf(oz, oz, q2);
    s3 += ow; q3 = fmaf(ow, ow, q3);
  }

  atomicAdd(&ls[ch+0], s0); atomicAdd(&ls[H+ch+0], q0);
  atomicAdd(&ls[ch+1], s1); atomicAdd(&ls[H+ch+1], q1);
  atomicAdd(&ls[ch+2], s2); atomicAdd(&ls[H+ch+2], q2);
  atomicAdd(&ls[ch+3], s3); atomicAdd(&ls[H+ch+3], q3);
  __syncthreads();
  atomicAdd(&stats[t], ls[t]);   // t in [0,512) == [0,2H)
}

// ---------- fused BN(layer2) + pooling + MLP ----------
__global__ __launch_bounds__(256) void pool_mlp_k(
    const ushort* __restrict__ hb, const ushort* __restrict__ aggb,
    const float* __restrict__ stats, const float* __restrict__ g2,
    const float* __restrict__ be2, const int* __restrict__ gstart,
    const float* __restrict__ mW1, const float* __restrict__ mb1,
    const float* __restrict__ mW2, const float* __restrict__ mb2,
    float* __restrict__ out, float invN) {
  int g = blockIdx.x, t = threadIdx.x; // 256 threads, t = channel
  __shared__ float p[H];
  __shared__ float mid[128];
  float mu  = stats[t]*invN;
  float var = stats[H+t]*invN - mu*mu;
  float sc  = g2[t]*rsqrtf(var+EPS);
  float sh  = be2[t] - mu*sc;
  int s = gstart[g], e = gstart[g+1];
  float sum = 0.f;
  for (int n = s; n < e; n++) {
    float av = b2f(aggb[(size_t)n*H + t]);
    float hv = b2f(hb[(size_t)n*H + t]);
    sum += fmaxf(fmaf(av, sc, sh), 0.f) + hv;
  }
  float cnt = fmaxf((float)(e - s), 1.f);
  p[t] = sum/cnt + sum;
  __syncthreads();
  if (t < 128) {
    float a = mb1[t];
    for (int k = 0; k < H; k++) a = fmaf(p[k], mW1[(size_t)k*128 + t], a);
    a = fmaxf(a, 0.f);
    mid[t] = a * mW2[t];
  }
  __syncthreads();
  for (int off = 64; off > 0; off >>= 1) {
    if (t < off) mid[t] += mid[t+off];
    __syncthreads();
  }
  if (t == 0) out[g] = mid[0] + mb2[0];
}

extern "C" void kernel_launch(void* const* d_in, const int* in_sizes, int n_in,
                              void* d_out, int out_size, void* d_ws, size_t ws_size,
                              hipStream_t stream) {
  const float* x        = (const float*)d_in[0];
  const void*  ei_raw   = d_in[1];
  const void*  batch_raw= d_in[2];
  const float* W0 = (const float*)d_in[3];
  const float* b0 = (const float*)d_in[4];
  const float* g0 = (const float*)d_in[5];
  const float* be0= (const float*)d_in[6];
  const float* W1 = (const float*)d_in[7];
  const float* b1 = (const float*)d_in[8];
  const float* g1 = (const float*)d_in[9];
  const float* be1= (const float*)d_in[10];
  const float* W2 = (const float*)d_in[11];
  const float* b2 = (const float*)d_in[12];
  const float* g2 = (const float*)d_in[13];
  const float* be2= (const float*)d_in[14];
  const float* mW1= (const float*)d_in[15];
  const float* mb1= (const float*)d_in[16];
  const float* mW2= (const float*)d_in[17];
  const float* mb2= (const float*)d_in[18];
  float* out = (float*)d_out;

  int N_ = in_sizes[2];
  int E_ = in_sizes[1] / 2;
  int F_ = in_sizes[0] / N_;
  int G_ = out_size;

  char* ws = (char*)d_ws;
  size_t off = 0;
  auto alloc = [&](size_t bytes) -> void* {
    void* p = ws + off;
    off = (off + bytes + 255) & ~(size_t)255;
    return p;
  };
  ushort* aggb   = (ushort*)alloc((size_t)N_*H*2);
  ushort* y      = (ushort*)alloc((size_t)N_*H*2);
  ushort* hb     = (ushort*)alloc((size_t)N_*H*2);
  ushort* xs     = (ushort*)alloc((size_t)N_*F_*2);
  ushort* z      = (ushort*)alloc((size_t)N_*F_*2);
  ushort* Wt0    = (ushort*)alloc((size_t)F_*H*2);
  ushort* Wt1    = (ushort*)alloc((size_t)H*H*2);
  ushort* Wt2    = (ushort*)alloc((size_t)H*H*2);
  int*    eidx   = (int*)   alloc((size_t)2*E_*4);
  int*    csr    = (int*)   alloc((size_t)E_*4);
  int*    batch  = (int*)   alloc((size_t)N_*4);
  int*    cnt    = (int*)   alloc((size_t)N_*4);
  int*    fill   = (int*)   alloc((size_t)N_*4);
  int*    rowptr = (int*)   alloc((size_t)(N_+1)*4);
  int*    bsum   = (int*)   alloc((size_t)((N_+1023)/1024 + 64)*4);
  float*  dinv   = (float*) alloc((size_t)N_*4);
  float*  stats  = (float*) alloc(6*H*4);   // stats0 | stats1 | stats2
  int*    gstart = (int*)   alloc((size_t)(G_+1)*4);
  int*    flag   = (int*)   alloc(4);
  float*  stats0 = stats;
  float*  stats1 = stats + 2*H;
  float*  stats2 = stats + 4*H;

  // index preprocessing (degree count fused into edge-index convert)
  detect_i64_k<<<1, 64, 0, stream>>>((const int*)ei_raw, flag);
  hipMemsetAsync(cnt, 0, (size_t)N_*4, stream);
  hipMemsetAsync(fill, 0, (size_t)N_*4, stream);
  hipMemsetAsync(stats, 0, 6*H*4, stream);
  convert_idx_k<<<(2*E_+255)/256, 256, 0, stream>>>(ei_raw, flag, eidx, 2*E_, cnt, E_);
  convert_idx_k<<<(N_+255)/256, 256, 0, stream>>>(batch_raw, flag, batch, N_, nullptr, 0);
  int nb1 = (N_ + 1023) / 1024;
  scan1_k<<<nb1, 256, 0, stream>>>(cnt, rowptr, bsum, dinv, N_);
  scan2_k<<<1, 64, 0, stream>>>(bsum, rowptr, nb1, N_);
  scan3_k<<<nb1, 256, 0, stream>>>(rowptr, bsum, N_);
  fill_csr_k<<<(E_+255)/256, 256, 0, stream>>>(eidx, eidx + E_, rowptr, fill, csr, E_);
  graph_starts_k<<<(G_+256)/256, 256, 0, stream>>>(batch, gstart, N_, G_);

  // converts
  int ksh0 = 31 - __builtin_clz(F_);
  xs_k<<<((N_*F_/4)+255)/256, 256, 0, stream>>>(x, dinv, xs, N_*F_/4, F_);
  int wtot = F_*H + 2*H*H;
  wt3_k<<<(wtot+255)/256, 256, 0, stream>>>(W0, W1, W2, Wt0, Wt1, Wt2, ksh0, F_*H);

  float invN = 1.0f / (float)N_;
  int nb = (N_ + 63) / 64;

  // ---- layer 0: aggregate0 -> GEMM(z,W0)+bias+stats0 ----
  aggregate0_k<<<512, 1024, 0, stream>>>(xs, csr, rowptr, dinv, z, N_, F_);
  if (F_ == 128)
    gemm_mfma_k<128,1,0,0><<<nb, 256, 0, stream>>>(z, Wt0, dinv, b0, nullptr, nullptr,
        nullptr, nullptr, y, aggb, stats0, N_, invN);
  else
    gemm_mfma_k<256,1,0,0><<<nb, 256, 0, stream>>>(z, Wt0, dinv, b0, nullptr, nullptr,
        nullptr, nullptr, y, aggb, stats0, N_, invN);

  // ---- layer 1: GEMM(h0=relu(bn0(aggb)),W1) fused -> aggregate+stats1 ----
  gemm_mfma_k<256,0,1,0><<<nb, 256, 0, stream>>>(aggb, Wt1, dinv, b1, stats0, g0,
      be0, hb, y, nullptr, nullptr, N_, invN);
  aggregate_k<<<2048, 512, 0, stream>>>(y, csr, rowptr, dinv, b1, aggb, stats1, N_);

  // ---- layer 2: GEMM(h1=h0+relu(bn1(aggb)),W2) fused -> aggregate+stats2 ----
  gemm_mfma_k<256,0,1,1><<<nb, 256, 0, stream>>>(aggb, Wt2, dinv, b2, stats1, g1,
      be1, hb, y, nullptr, nullptr, N_, invN);
  aggregate_k<<<2048, 512, 0, stream>>>(y, csr, rowptr, dinv, b2, aggb, stats2, N_);

  // ---- fused bn2 + pool + MLP (all graphs; empty ones yield the constant) ----
  pool_mlp_k<<<G_, 256, 0, stream>>>(hb, aggb, stats2, g2, be2, gstart,
      mW1, mb1, mW2, mb2, out, invN);
}

// Round 15
// 487.162 us; speedup vs baseline: 1.1448x; 1.1448x over previous
//
#include <hip/hip_runtime.h>
#include <math.h>

#define H 256
#define EPS 1e-5f

typedef __attribute__((ext_vector_type(8))) short bf16x8;
typedef __attribute__((ext_vector_type(4))) float f32x4;

__device__ inline ushort f2b(float f) {
  union { float f; unsigned u; } v; v.f = f;
  unsigned r = v.u + 0x7FFF + ((v.u >> 16) & 1);
  return (ushort)(r >> 16);
}
__device__ inline float b2f(ushort u) {
  union { unsigned u; float f; } v; v.u = ((unsigned)u) << 16;
  return v.f;
}

// ---------- index dtype detection & conversion (+fused degree count) ----------
__global__ void detect_i64_k(const int* __restrict__ w, int* __restrict__ flag) {
  if (threadIdx.x == 0 && blockIdx.x == 0) {
    int all0 = 1;
    for (int k = 0; k < 64; k++) if (w[2*k+1] != 0) { all0 = 0; break; }
    *flag = all0;
  }
}

__global__ void convert_idx_k(const void* __restrict__ raw, const int* __restrict__ flag,
                              int* __restrict__ out, int n,
                              int* __restrict__ cnt, int countFrom) {
  int i = blockIdx.x*256 + threadIdx.x;
  if (i >= n) return;
  int v;
  if (*flag) v = (int)((const long long*)raw)[i];
  else       v = ((const int*)raw)[i];
  out[i] = v;
  if (cnt && i >= countFrom) atomicAdd(&cnt[v], 1);
}

// ---------- hierarchical exclusive scan (+fused dinv) ----------
__global__ void scan1_k(const int* __restrict__ cnt, int* __restrict__ rowptr,
                        int* __restrict__ bsum, float* __restrict__ dinv, int N_) {
  __shared__ int sh[256];
  int t = threadIdx.x;
  int i0 = blockIdx.x*1024 + t*4;
  int v0=0,v1=0,v2=0,v3=0;
  if (i0+0 < N_) v0 = cnt[i0+0];
  if (i0+1 < N_) v1 = cnt[i0+1];
  if (i0+2 < N_) v2 = cnt[i0+2];
  if (i0+3 < N_) v3 = cnt[i0+3];
  if (i0+0 < N_) dinv[i0+0] = rsqrtf((float)v0 + 1.0f);
  if (i0+1 < N_) dinv[i0+1] = rsqrtf((float)v1 + 1.0f);
  if (i0+2 < N_) dinv[i0+2] = rsqrtf((float)v2 + 1.0f);
  if (i0+3 < N_) dinv[i0+3] = rsqrtf((float)v3 + 1.0f);
  sh[t] = v0+v1+v2+v3;
  __syncthreads();
  for (int off = 1; off < 256; off <<= 1) {
    int x = (t >= off) ? sh[t-off] : 0;
    __syncthreads();
    sh[t] += x;
    __syncthreads();
  }
  int excl = (t == 0) ? 0 : sh[t-1];
  if (i0+0 < N_) rowptr[i0+0] = excl;
  if (i0+1 < N_) rowptr[i0+1] = excl+v0;
  if (i0+2 < N_) rowptr[i0+2] = excl+v0+v1;
  if (i0+3 < N_) rowptr[i0+3] = excl+v0+v1+v2;
  if (t == 255) bsum[blockIdx.x] = sh[255];
}

__global__ void scan2_k(int* __restrict__ bsum, int* __restrict__ rowptr,
                        int nb, int N_) {
  int lane = threadIdx.x; // 64 threads
  int carry = 0;
  for (int base = 0; base < nb; base += 64) {
    int i = base + lane;
    int orig = (i < nb) ? bsum[i] : 0;
    int v = orig;
    for (int off = 1; off < 64; off <<= 1) {
      int u = __shfl_up(v, off);
      if (lane >= off) v += u;
    }
    if (i < nb) bsum[i] = carry + v - orig; // exclusive
    carry += __shfl(v, 63);
  }
  if (lane == 0) rowptr[N_] = carry;
}

__global__ void scan3_k(int* __restrict__ rowptr, const int* __restrict__ bsum, int N_) {
  int off = bsum[blockIdx.x];
  int i = blockIdx.x*1024 + threadIdx.x*4;
#pragma unroll
  for (int k = 0; k < 4; k++) if (i+k < N_) rowptr[i+k] += off;
}

__global__ void fill_csr_k(const int* __restrict__ row, const int* __restrict__ col,
                           const int* __restrict__ rowptr, int* __restrict__ fill,
                           int* __restrict__ src, int E_) {
  int e = blockIdx.x*256 + threadIdx.x;
  if (e < E_) {
    int c = col[e];
    int p = rowptr[c] + atomicAdd(&fill[c], 1);
    src[p] = row[e];
  }
}

__global__ void graph_starts_k(const int* __restrict__ batch, int* __restrict__ gstart,
                               int N_, int G_) {
  int g = blockIdx.x*256 + threadIdx.x;
  if (g > G_) return;
  int lo = 0, hi = N_;
  while (lo < hi) { int m = (lo+hi) >> 1; if (batch[m] < g) lo = m+1; else hi = m; }
  gstart[g] = lo;
}

// ---------- xs[r][f] = bf16(dinv[r] * x[r][f]) ----------
__global__ void xs_k(const float* __restrict__ x, const float* __restrict__ dinv,
                     ushort* __restrict__ xs, int n4, int F_) {
  int i = blockIdx.x*256 + threadIdx.x;
  if (i >= n4) return;
  int row = (i << 2) / F_;
  float dv = dinv[row];
  float4 v = ((const float4*)x)[i];
  ushort4 o;
  o.x = f2b(v.x*dv); o.y = f2b(v.y*dv); o.z = f2b(v.z*dv); o.w = f2b(v.w*dv);
  ((ushort4*)xs)[i] = o;
}

// ---------- all three weight transposes in one kernel ----------
__global__ void wt3_k(const float* __restrict__ W0, const float* __restrict__ W1,
                      const float* __restrict__ W2, ushort* __restrict__ Wt0,
                      ushort* __restrict__ Wt1, ushort* __restrict__ Wt2,
                      int ksh0, int n0) {
  int idx = blockIdx.x*256 + threadIdx.x;
  if (idx < n0) {
    int n = idx >> ksh0, k = idx & ((1 << ksh0) - 1);
    Wt0[idx] = f2b(W0[(size_t)k*H + n]);
  } else if (idx < n0 + H*H) {
    int j = idx - n0;
    int n = j >> 8, k = j & 255;
    Wt1[j] = f2b(W1[(size_t)k*H + n]);
  } else if (idx < n0 + 2*H*H) {
    int j = idx - n0 - H*H;
    int n = j >> 8, k = j & 255;
    Wt2[j] = f2b(W2[(size_t)k*H + n]);
  }
}

// ---------- layer-0 aggregation on F channels: z = bf16(Â x) ----------
__global__ __launch_bounds__(1024) void aggregate0_k(
    const ushort* __restrict__ xs, const int* __restrict__ src,
    const int* __restrict__ rowptr, const float* __restrict__ dinv,
    ushort* __restrict__ z, int N_, int F_) {
  int t = threadIdx.x;
  int lane = t & 63, wv = t >> 6;
  int ch = lane * 2;
  for (int c = blockIdx.x*16 + wv; c < N_; c += gridDim.x*16) {
    float di = dinv[c];
    ushort2 sv = *(const ushort2*)(xs + (size_t)c*F_ + ch);
    float a0 = b2f(sv.x), b0 = b2f(sv.y);
    float a1=0.f,b1=0.f,a2=0.f,b2=0.f,a3=0.f,b3=0.f;
    int s = rowptr[c], e = rowptr[c+1];
    int j = s;
    for (; j + 8 <= e; j += 8) {
      int r0 = src[j],   r1 = src[j+1], r2 = src[j+2], r3 = src[j+3];
      int r4 = src[j+4], r5 = src[j+5], r6 = src[j+6], r7 = src[j+7];
      ushort2 v0 = *(const ushort2*)(xs + (size_t)r0*F_ + ch);
      ushort2 v1 = *(const ushort2*)(xs + (size_t)r1*F_ + ch);
      ushort2 v2 = *(const ushort2*)(xs + (size_t)r2*F_ + ch);
      ushort2 v3 = *(const ushort2*)(xs + (size_t)r3*F_ + ch);
      ushort2 v4 = *(const ushort2*)(xs + (size_t)r4*F_ + ch);
      ushort2 v5 = *(const ushort2*)(xs + (size_t)r5*F_ + ch);
      ushort2 v6 = *(const ushort2*)(xs + (size_t)r6*F_ + ch);
      ushort2 v7 = *(const ushort2*)(xs + (size_t)r7*F_ + ch);
      a0 += b2f(v0.x); b0 += b2f(v0.y);
      a1 += b2f(v1.x); b1 += b2f(v1.y);
      a2 += b2f(v2.x); b2 += b2f(v2.y);
      a3 += b2f(v3.x); b3 += b2f(v3.y);
      a0 += b2f(v4.x); b0 += b2f(v4.y);
      a1 += b2f(v5.x); b1 += b2f(v5.y);
      a2 += b2f(v6.x); b2 += b2f(v6.y);
      a3 += b2f(v7.x); b3 += b2f(v7.y);
    }
    for (; j + 4 <= e; j += 4) {
      int r0 = src[j], r1 = src[j+1], r2 = src[j+2], r3 = src[j+3];
      ushort2 v0 = *(const ushort2*)(xs + (size_t)r0*F_ + ch);
      ushort2 v1 = *(const ushort2*)(xs + (size_t)r1*F_ + ch);
      ushort2 v2 = *(const ushort2*)(xs + (size_t)r2*F_ + ch);
      ushort2 v3 = *(const ushort2*)(xs + (size_t)r3*F_ + ch);
      a0 += b2f(v0.x); b0 += b2f(v0.y);
      a1 += b2f(v1.x); b1 += b2f(v1.y);
      a2 += b2f(v2.x); b2 += b2f(v2.y);
      a3 += b2f(v3.x); b3 += b2f(v3.y);
    }
    for (; j < e; j++) {
      int r = src[j];
      ushort2 v = *(const ushort2*)(xs + (size_t)r*F_ + ch);
      a0 += b2f(v.x); b0 += b2f(v.y);
    }
    float sa = (a0+a1)+(a2+a3);
    float sb = (b0+b1)+(b2+b3);
    ushort2 o; o.x = f2b(sa*di); o.y = f2b(sb*di);
    *(ushort2*)(z + (size_t)c*F_ + ch) = o;
  }
}

// ---------- GEMM with LDS-staged A tile, deep-pipelined (R12 version) ----------
template<int K, int MODE, int FUSE, int RES>
__global__ __launch_bounds__(256) void gemm_mfma_k(
    const ushort* __restrict__ A, const ushort* __restrict__ Wt,
    const float* __restrict__ dinv, const float* __restrict__ bias,
    const float* __restrict__ stats, const float* __restrict__ g,
    const float* __restrict__ beta, ushort* __restrict__ hb,
    ushort* __restrict__ y, ushort* __restrict__ aggb_out,
    float* __restrict__ statsout, int N_, float invN) {
  __shared__ ushort At[64*256];
  __shared__ float scsh[2*H];
  __shared__ float ls[2*H];
  int t = threadIdx.x;
  int lane = t & 63, w = t >> 6;
  int r0 = blockIdx.x * 64;
  int c0 = w * 64;
  int lr = lane & 15, lk = (lane >> 4) * 8;
  const int ROWB = K*2;

  if (FUSE) {
    float mu  = stats[t]*invN;
    float var = stats[H+t]*invN - mu*mu;
    float sc  = g[t]*rsqrtf(var+EPS);
    scsh[t] = sc; scsh[H+t] = beta[t] - mu*sc;
    __syncthreads();
  }
  constexpr int C4PR = K/4;
  constexpr int ITER = 64*C4PR/256;
#pragma unroll
  for (int it = 0; it < ITER; it++) {
    int idx = it*256 + t;
    int row = idx / C4PR;
    int c4 = (idx % C4PR) * 4;
    int grow = r0 + row;
    int gr = (grow < N_) ? grow : (N_-1);
    ushort4 av = *(const ushort4*)(A + (size_t)gr*K + c4);
    ushort4 o;
    if (FUSE) {
      float x0 = fmaxf(fmaf(b2f(av.x), scsh[c4+0], scsh[H+c4+0]), 0.f);
      float x1 = fmaxf(fmaf(b2f(av.y), scsh[c4+1], scsh[H+c4+1]), 0.f);
      float x2 = fmaxf(fmaf(b2f(av.z), scsh[c4+2], scsh[H+c4+2]), 0.f);
      float x3 = fmaxf(fmaf(b2f(av.w), scsh[c4+3], scsh[H+c4+3]), 0.f);
      if (RES) {
        ushort4 hv = *(const ushort4*)(hb + (size_t)gr*K + c4);
        x0 += b2f(hv.x); x1 += b2f(hv.y); x2 += b2f(hv.z); x3 += b2f(hv.w);
      }
      o.x = f2b(x0); o.y = f2b(x1); o.z = f2b(x2); o.w = f2b(x3);
      if (grow < N_) *(ushort4*)(hb + (size_t)grow*K + c4) = o;
    } else {
      o = av;
    }
    int byte = row*ROWB + ((c4*2) ^ ((row&7)<<4));
    *(ushort4*)((char*)At + byte) = o;
  }
  __syncthreads();

  f32x4 acc[4][4];
#pragma unroll
  for (int m = 0; m < 4; m++)
#pragma unroll
    for (int n = 0; n < 4; n++) acc[m][n] = (f32x4)0.f;

  const ushort* Wp[4];
#pragma unroll
  for (int n = 0; n < 4; n++) Wp[n] = Wt + (size_t)(c0 + n*16 + lr)*K + lk;

  const int NSTEP = K / 32;
  bf16x8 w0[4], w1[4], w2[4], a_cur[4], a_nxt[4];
#pragma unroll
  for (int n = 0; n < 4; n++) w0[n] = *(const bf16x8*)(Wp[n]);
#pragma unroll
  for (int n = 0; n < 4; n++) w1[n] = *(const bf16x8*)(Wp[n] + (NSTEP > 1 ? 32 : 0));
#pragma unroll
  for (int m = 0; m < 4; m++) {
    int row = m*16 + lr;
    int byte = row*ROWB + ((lk*2) ^ ((row&7)<<4));
    a_cur[m] = *(const bf16x8*)((const char*)At + byte);
  }

#pragma unroll
  for (int s = 0; s < NSTEP; s++) {
    if (s + 2 < NSTEP) {
      int k0 = (s + 2) * 32;
#pragma unroll
      for (int n = 0; n < 4; n++) w2[n] = *(const bf16x8*)(Wp[n] + k0);
    }
    if (s + 1 < NSTEP) {
#pragma unroll
      for (int m = 0; m < 4; m++) {
        int row = m*16 + lr;
        int byte = row*ROWB + ((((lk + (s+1)*32)*2)) ^ ((row&7)<<4));
        a_nxt[m] = *(const bf16x8*)((const char*)At + byte);
      }
    }
#pragma unroll
    for (int m = 0; m < 4; m++)
#pragma unroll
      for (int n = 0; n < 4; n++)
        acc[m][n] = __builtin_amdgcn_mfma_f32_16x16x32_bf16(a_cur[m], w0[n], acc[m][n], 0, 0, 0);
    if (s + 1 < NSTEP) {
#pragma unroll
      for (int n = 0; n < 4; n++) { w0[n] = w1[n]; }
#pragma unroll
      for (int m = 0; m < 4; m++) a_cur[m] = a_nxt[m];
    }
    if (s + 2 < NSTEP) {
#pragma unroll
      for (int n = 0; n < 4; n++) w1[n] = w2[n];
    }
  }

  int lrow = (lane >> 4) * 4;
  int lcol = lane & 15;

  if (MODE == 0) {
#pragma unroll
    for (int m = 0; m < 4; m++) {
#pragma unroll
      for (int r = 0; r < 4; r++) {
        int row = r0 + m*16 + lrow + r;
        if (row < N_) {
          float dv = dinv[row];
#pragma unroll
          for (int n = 0; n < 4; n++)
            y[(size_t)row*H + c0 + n*16 + lcol] = f2b(acc[m][n][r] * dv);
        }
      }
    }
  } else {
    ls[t] = 0.f; ls[t + H] = 0.f;
    __syncthreads();
    float bvn[4];
#pragma unroll
    for (int n = 0; n < 4; n++) bvn[n] = bias[c0 + n*16 + lcol];
    float sn[4] = {0.f,0.f,0.f,0.f}, qn[4] = {0.f,0.f,0.f,0.f};
#pragma unroll
    for (int m = 0; m < 4; m++) {
#pragma unroll
      for (int r = 0; r < 4; r++) {
        int row = r0 + m*16 + lrow + r;
        if (row < N_) {
#pragma unroll
          for (int n = 0; n < 4; n++) {
            float v = acc[m][n][r] + bvn[n];
            aggb_out[(size_t)row*H + c0 + n*16 + lcol] = f2b(v);
            sn[n] += v; qn[n] = fmaf(v, v, qn[n]);
          }
        }
      }
    }
#pragma unroll
    for (int n = 0; n < 4; n++) {
      atomicAdd(&ls[c0 + n*16 + lcol], sn[n]);
      atomicAdd(&ls[H + c0 + n*16 + lcol], qn[n]);
    }
    __syncthreads();
    atomicAdd(&statsout[t], ls[t]);
    atomicAdd(&statsout[H + t], ls[H + t]);
  }
}

// ---------- aggregation + fused BN stats (layers 1,2) — R12 1024-thread ----------
__global__ __launch_bounds__(1024) void aggregate_k(
    const ushort* __restrict__ y, const int* __restrict__ src,
    const int* __restrict__ rowptr, const float* __restrict__ dinv,
    const float* __restrict__ b, ushort* __restrict__ aggb,
    float* __restrict__ stats, int N_) {
  __shared__ float ls[2*H];
  int t = threadIdx.x;
  if (t < 2*H) ls[t] = 0.f;
  __syncthreads();

  int lane = t & 63, wv = t >> 6;
  int ch = lane * 4;
  float4 bv = *(const float4*)(b + ch);

  float s0=0.f, s1=0.f, s2=0.f, s3=0.f;
  float q0=0.f, q1=0.f, q2=0.f, q3=0.f;

  for (int c = blockIdx.x*16 + wv; c < N_; c += gridDim.x*16) {
    float di = dinv[c];
    ushort4 sv = *(const ushort4*)(y + (size_t)c*H + ch);
    float a0x = b2f(sv.x), a0y = b2f(sv.y), a0z = b2f(sv.z), a0w = b2f(sv.w);
    float a1x=0.f,a1y=0.f,a1z=0.f,a1w=0.f;
    float a2x=0.f,a2y=0.f,a2z=0.f,a2w=0.f;
    float a3x=0.f,a3y=0.f,a3z=0.f,a3w=0.f;
    int s = rowptr[c], e = rowptr[c+1];
    int j = s;
    for (; j + 8 <= e; j += 8) {
      int r0 = src[j],   r1 = src[j+1], r2 = src[j+2], r3 = src[j+3];
      int r4 = src[j+4], r5 = src[j+5], r6 = src[j+6], r7 = src[j+7];
      ushort4 v0 = *(const ushort4*)(y + (size_t)r0*H + ch);
      ushort4 v1 = *(const ushort4*)(y + (size_t)r1*H + ch);
      ushort4 v2 = *(const ushort4*)(y + (size_t)r2*H + ch);
      ushort4 v3 = *(const ushort4*)(y + (size_t)r3*H + ch);
      ushort4 v4 = *(const ushort4*)(y + (size_t)r4*H + ch);
      ushort4 v5 = *(const ushort4*)(y + (size_t)r5*H + ch);
      ushort4 v6 = *(const ushort4*)(y + (size_t)r6*H + ch);
      ushort4 v7 = *(const ushort4*)(y + (size_t)r7*H + ch);
      a0x += b2f(v0.x); a0y += b2f(v0.y); a0z += b2f(v0.z); a0w += b2f(v0.w);
      a1x += b2f(v1.x); a1y += b2f(v1.y); a1z += b2f(v1.z); a1w += b2f(v1.w);
      a2x += b2f(v2.x); a2y += b2f(v2.y); a2z += b2f(v2.z); a2w += b2f(v2.w);
      a3x += b2f(v3.x); a3y += b2f(v3.y); a3z += b2f(v3.z); a3w += b2f(v3.w);
      a0x += b2f(v4.x); a0y += b2f(v4.y); a0z += b2f(v4.z); a0w += b2f(v4.w);
      a1x += b2f(v5.x); a1y += b2f(v5.y); a1z += b2f(v5.z); a1w += b2f(v5.w);
      a2x += b2f(v6.x); a2y += b2f(v6.y); a2z += b2f(v6.z); a2w += b2f(v6.w);
      a3x += b2f(v7.x); a3y += b2f(v7.y); a3z += b2f(v7.z); a3w += b2f(v7.w);
    }
    for (; j + 4 <= e; j += 4) {
      int r0 = src[j], r1 = src[j+1], r2 = src[j+2], r3 = src[j+3];
      ushort4 v0 = *(const ushort4*)(y + (size_t)r0*H + ch);
      ushort4 v1 = *(const ushort4*)(y + (size_t)r1*H + ch);
      ushort4 v2 = *(const ushort4*)(y + (size_t)r2*H + ch);
      ushort4 v3 = *(const ushort4*)(y + (size_t)r3*H + ch);
      a0x += b2f(v0.x); a0y += b2f(v0.y); a0z += b2f(v0.z); a0w += b2f(v0.w);
      a1x += b2f(v1.x); a1y += b2f(v1.y); a1z += b2f(v1.z); a1w += b2f(v1.w);
      a2x += b2f(v2.x); a2y += b2f(v2.y); a2z += b2f(v2.z); a2w += b2f(v2.w);
      a3x += b2f(v3.x); a3y += b2f(v3.y); a3z += b2f(v3.z); a3w += b2f(v3.w);
    }
    for (; j < e; j++) {
      int r = src[j];
      ushort4 v = *(const ushort4*)(y + (size_t)r*H + ch);
      a0x += b2f(v.x); a0y += b2f(v.y); a0z += b2f(v.z); a0w += b2f(v.w);
    }
    float ax = (a0x + a1x) + (a2x + a3x);
    float ay = (a0y + a1y) + (a2y + a3y);
    float az = (a0z + a1z) + (a2z + a3z);
    float aw = (a0w + a1w) + (a2w + a3w);
    float ox = fmaf(ax, di, bv.x);
    float oy = fmaf(ay, di, bv.y);
    float oz = fmaf(az, di, bv.z);
    float ow = fmaf(aw, di, bv.w);
    ushort4 ob; ob.x = f2b(ox); ob.y = f2b(oy); ob.z = f2b(oz); ob.w = f2b(ow);
    *(ushort4*)(aggb + (size_t)c*H + ch) = ob;
    s0 += ox; q0 = fmaf(ox, ox, q0);
    s1 += oy; q1 = fmaf(oy, oy, q1);
    s2 += oz; q2 = fmaf(oz, oz, q2);
    s3 += ow; q3 = fmaf(ow, ow, q3);
  }

  atomicAdd(&ls[ch+0], s0); atomicAdd(&ls[H+ch+0], q0);
  atomicAdd(&ls[ch+1], s1); atomicAdd(&ls[H+ch+1], q1);
  atomicAdd(&ls[ch+2], s2); atomicAdd(&ls[H+ch+2], q2);
  atomicAdd(&ls[ch+3], s3); atomicAdd(&ls[H+ch+3], q3);
  __syncthreads();
  if (t < 2*H) atomicAdd(&stats[t], ls[t]);
}

// ---------- fused BN(layer2) + pooling + MLP (empty graphs skip k-loop) ----------
__global__ __launch_bounds__(256) void pool_mlp_k(
    const ushort* __restrict__ hb, const ushort* __restrict__ aggb,
    const float* __restrict__ stats, const float* __restrict__ g2,
    const float* __restrict__ be2, const int* __restrict__ gstart,
    const float* __restrict__ mW1, const float* __restrict__ mb1,
    const float* __restrict__ mW2, const float* __restrict__ mb2,
    float* __restrict__ out, float invN) {
  int g = blockIdx.x, t = threadIdx.x; // 256 threads, t = channel
  __shared__ float p[H];
  __shared__ float mid[128];
  int s = gstart[g], e = gstart[g+1];
  int nonempty = (e > s);
  if (nonempty) {
    float mu  = stats[t]*invN;
    float var = stats[H+t]*invN - mu*mu;
    float sc  = g2[t]*rsqrtf(var+EPS);
    float sh  = be2[t] - mu*sc;
    float sum = 0.f;
    for (int n = s; n < e; n++) {
      float av = b2f(aggb[(size_t)n*H + t]);
      float hv = b2f(hb[(size_t)n*H + t]);
      sum += fmaxf(fmaf(av, sc, sh), 0.f) + hv;
    }
    float cnt = (float)(e - s);
    p[t] = sum/cnt + sum;
  }
  __syncthreads();
  if (t < 128) {
    float a = mb1[t];
    if (nonempty) {
      for (int k = 0; k < H; k++) a = fmaf(p[k], mW1[(size_t)k*128 + t], a);
    }
    a = fmaxf(a, 0.f);
    mid[t] = a * mW2[t];
  }
  __syncthreads();
  for (int off = 64; off > 0; off >>= 1) {
    if (t < off) mid[t] += mid[t+off];
    __syncthreads();
  }
  if (t == 0) out[g] = mid[0] + mb2[0];
}

extern "C" void kernel_launch(void* const* d_in, const int* in_sizes, int n_in,
                              void* d_out, int out_size, void* d_ws, size_t ws_size,
                              hipStream_t stream) {
  const float* x        = (const float*)d_in[0];
  const void*  ei_raw   = d_in[1];
  const void*  batch_raw= d_in[2];
  const float* W0 = (const float*)d_in[3];
  const float* b0 = (const float*)d_in[4];
  const float* g0 = (const float*)d_in[5];
  const float* be0= (const float*)d_in[6];
  const float* W1 = (const float*)d_in[7];
  const float* b1 = (const float*)d_in[8];
  const float* g1 = (const float*)d_in[9];
  const float* be1= (const float*)d_in[10];
  const float* W2 = (const float*)d_in[11];
  const float* b2 = (const float*)d_in[12];
  const float* g2 = (const float*)d_in[13];
  const float* be2= (const float*)d_in[14];
  const float* mW1= (const float*)d_in[15];
  const float* mb1= (const float*)d_in[16];
  const float* mW2= (const float*)d_in[17];
  const float* mb2= (const float*)d_in[18];
  float* out = (float*)d_out;

  int N_ = in_sizes[2];
  int E_ = in_sizes[1] / 2;
  int F_ = in_sizes[0] / N_;
  int G_ = out_size;

  char* ws = (char*)d_ws;
  size_t off = 0;
  auto alloc = [&](size_t bytes) -> void* {
    void* p = ws + off;
    off = (off + bytes + 255) & ~(size_t)255;
    return p;
  };
  ushort* aggb   = (ushort*)alloc((size_t)N_*H*2);
  ushort* y      = (ushort*)alloc((size_t)N_*H*2);
  ushort* hb     = (ushort*)alloc((size_t)N_*H*2);
  ushort* xs     = (ushort*)alloc((size_t)N_*F_*2);
  ushort* z      = (ushort*)alloc((size_t)N_*F_*2);
  ushort* Wt0    = (ushort*)alloc((size_t)F_*H*2);
  ushort* Wt1    = (ushort*)alloc((size_t)H*H*2);
  ushort* Wt2    = (ushort*)alloc((size_t)H*H*2);
  int*    eidx   = (int*)   alloc((size_t)2*E_*4);
  int*    csr    = (int*)   alloc((size_t)E_*4);
  int*    batch  = (int*)   alloc((size_t)N_*4);
  int*    cnt    = (int*)   alloc((size_t)N_*4);
  int*    fill   = (int*)   alloc((size_t)N_*4);
  int*    rowptr = (int*)   alloc((size_t)(N_+1)*4);
  int*    bsum   = (int*)   alloc((size_t)((N_+1023)/1024 + 64)*4);
  float*  dinv   = (float*) alloc((size_t)N_*4);
  float*  stats  = (float*) alloc(6*H*4);   // stats0 | stats1 | stats2
  int*    gstart = (int*)   alloc((size_t)(G_+1)*4);
  int*    flag   = (int*)   alloc(4);
  float*  stats0 = stats;
  float*  stats1 = stats + 2*H;
  float*  stats2 = stats + 4*H;

  // index preprocessing (degree count fused into edge-index convert)
  detect_i64_k<<<1, 64, 0, stream>>>((const int*)ei_raw, flag);
  hipMemsetAsync(cnt, 0, (size_t)N_*4, stream);
  hipMemsetAsync(fill, 0, (size_t)N_*4, stream);
  hipMemsetAsync(stats, 0, 6*H*4, stream);
  convert_idx_k<<<(2*E_+255)/256, 256, 0, stream>>>(ei_raw, flag, eidx, 2*E_, cnt, E_);
  convert_idx_k<<<(N_+255)/256, 256, 0, stream>>>(batch_raw, flag, batch, N_, nullptr, 0);
  int nb1 = (N_ + 1023) / 1024;
  scan1_k<<<nb1, 256, 0, stream>>>(cnt, rowptr, bsum, dinv, N_);
  scan2_k<<<1, 64, 0, stream>>>(bsum, rowptr, nb1, N_);
  scan3_k<<<nb1, 256, 0, stream>>>(rowptr, bsum, N_);
  fill_csr_k<<<(E_+255)/256, 256, 0, stream>>>(eidx, eidx + E_, rowptr, fill, csr, E_);
  graph_starts_k<<<(G_+256)/256, 256, 0, stream>>>(batch, gstart, N_, G_);

  // converts
  int ksh0 = 31 - __builtin_clz(F_);
  xs_k<<<((N_*F_/4)+255)/256, 256, 0, stream>>>(x, dinv, xs, N_*F_/4, F_);
  int wtot = F_*H + 2*H*H;
  wt3_k<<<(wtot+255)/256, 256, 0, stream>>>(W0, W1, W2, Wt0, Wt1, Wt2, ksh0, F_*H);

  float invN = 1.0f / (float)N_;
  int nb = (N_ + 63) / 64;

  // ---- layer 0: aggregate0 -> GEMM(z,W0)+bias+stats0 ----
  aggregate0_k<<<512, 1024, 0, stream>>>(xs, csr, rowptr, dinv, z, N_, F_);
  if (F_ == 128)
    gemm_mfma_k<128,1,0,0><<<nb, 256, 0, stream>>>(z, Wt0, dinv, b0, nullptr, nullptr,
        nullptr, nullptr, y, aggb, stats0, N_, invN);
  else
    gemm_mfma_k<256,1,0,0><<<nb, 256, 0, stream>>>(z, Wt0, dinv, b0, nullptr, nullptr,
        nullptr, nullptr, y, aggb, stats0, N_, invN);

  // ---- layer 1: GEMM(h0=relu(bn0(aggb)),W1) fused -> aggregate+stats1 ----
  gemm_mfma_k<256,0,1,0><<<nb, 256, 0, stream>>>(aggb, Wt1, dinv, b1, stats0, g0,
      be0, hb, y, nullptr, nullptr, N_, invN);
  aggregate_k<<<512, 1024, 0, stream>>>(y, csr, rowptr, dinv, b1, aggb, stats1, N_);

  // ---- layer 2: GEMM(h1=h0+relu(bn1(aggb)),W2) fused -> aggregate+stats2 ----
  gemm_mfma_k<256,0,1,1><<<nb, 256, 0, stream>>>(aggb, Wt2, dinv, b2, stats1, g1,
      be1, hb, y, nullptr, nullptr, N_, invN);
  aggregate_k<<<512, 1024, 0, stream>>>(y, csr, rowptr, dinv, b2, aggb, stats2, N_);

  // ---- fused bn2 + pool + MLP (all graphs; empty ones skip the k-loop) ----
  pool_mlp_k<<<G_, 256, 0, stream>>>(hb, aggb, stats2, g2, be2, gstart,
      mW1, mb1, mW2, mb2, out, invN);
}

// Round 16
// 459.329 us; speedup vs baseline: 1.2142x; 1.0606x over previous
//
#include <hip/hip_runtime.h>
#include <math.h>

#define H 256
#define EPS 1e-5f

typedef __attribute__((ext_vector_type(8))) short bf16x8;
typedef __attribute__((ext_vector_type(4))) float f32x4;

__device__ inline ushort f2b(float f) {
  union { float f; unsigned u; } v; v.f = f;
  unsigned r = v.u + 0x7FFF + ((v.u >> 16) & 1);
  return (ushort)(r >> 16);
}
__device__ inline float b2f(ushort u) {
  union { unsigned u; float f; } v; v.u = ((unsigned)u) << 16;
  return v.f;
}

// ---------- index dtype detection & conversion (+fused degree count) ----------
__global__ void detect_i64_k(const int* __restrict__ w, int* __restrict__ flag) {
  if (threadIdx.x == 0 && blockIdx.x == 0) {
    int all0 = 1;
    for (int k = 0; k < 64; k++) if (w[2*k+1] != 0) { all0 = 0; break; }
    *flag = all0;
  }
}

__global__ void convert_idx_k(const void* __restrict__ raw, const int* __restrict__ flag,
                              int* __restrict__ out, int n,
                              int* __restrict__ cnt, int countFrom) {
  int i = blockIdx.x*256 + threadIdx.x;
  if (i >= n) return;
  int v;
  if (*flag) v = (int)((const long long*)raw)[i];
  else       v = ((const int*)raw)[i];
  out[i] = v;
  if (cnt && i >= countFrom) atomicAdd(&cnt[v], 1);
}

// ---------- hierarchical exclusive scan (+fused dinv) ----------
__global__ void scan1_k(const int* __restrict__ cnt, int* __restrict__ rowptr,
                        int* __restrict__ bsum, float* __restrict__ dinv, int N_) {
  __shared__ int sh[256];
  int t = threadIdx.x;
  int i0 = blockIdx.x*1024 + t*4;
  int v0=0,v1=0,v2=0,v3=0;
  if (i0+0 < N_) v0 = cnt[i0+0];
  if (i0+1 < N_) v1 = cnt[i0+1];
  if (i0+2 < N_) v2 = cnt[i0+2];
  if (i0+3 < N_) v3 = cnt[i0+3];
  if (i0+0 < N_) dinv[i0+0] = rsqrtf((float)v0 + 1.0f);
  if (i0+1 < N_) dinv[i0+1] = rsqrtf((float)v1 + 1.0f);
  if (i0+2 < N_) dinv[i0+2] = rsqrtf((float)v2 + 1.0f);
  if (i0+3 < N_) dinv[i0+3] = rsqrtf((float)v3 + 1.0f);
  sh[t] = v0+v1+v2+v3;
  __syncthreads();
  for (int off = 1; off < 256; off <<= 1) {
    int x = (t >= off) ? sh[t-off] : 0;
    __syncthreads();
    sh[t] += x;
    __syncthreads();
  }
  int excl = (t == 0) ? 0 : sh[t-1];
  if (i0+0 < N_) rowptr[i0+0] = excl;
  if (i0+1 < N_) rowptr[i0+1] = excl+v0;
  if (i0+2 < N_) rowptr[i0+2] = excl+v0+v1;
  if (i0+3 < N_) rowptr[i0+3] = excl+v0+v1+v2;
  if (t == 255) bsum[blockIdx.x] = sh[255];
}

__global__ void scan2_k(int* __restrict__ bsum, int* __restrict__ rowptr,
                        int nb, int N_) {
  int lane = threadIdx.x; // 64 threads
  int carry = 0;
  for (int base = 0; base < nb; base += 64) {
    int i = base + lane;
    int orig = (i < nb) ? bsum[i] : 0;
    int v = orig;
    for (int off = 1; off < 64; off <<= 1) {
      int u = __shfl_up(v, off);
      if (lane >= off) v += u;
    }
    if (i < nb) bsum[i] = carry + v - orig; // exclusive
    carry += __shfl(v, 63);
  }
  if (lane == 0) rowptr[N_] = carry;
}

__global__ void scan3_k(int* __restrict__ rowptr, const int* __restrict__ bsum, int N_) {
  int off = bsum[blockIdx.x];
  int i = blockIdx.x*1024 + threadIdx.x*4;
#pragma unroll
  for (int k = 0; k < 4; k++) if (i+k < N_) rowptr[i+k] += off;
}

__global__ void fill_csr_k(const int* __restrict__ row, const int* __restrict__ col,
                           const int* __restrict__ rowptr, int* __restrict__ fill,
                           int* __restrict__ src, int E_) {
  int e = blockIdx.x*256 + threadIdx.x;
  if (e < E_) {
    int c = col[e];
    int p = rowptr[c] + atomicAdd(&fill[c], 1);
    src[p] = row[e];
  }
}

__global__ void graph_starts_k(const int* __restrict__ batch, int* __restrict__ gstart,
                               int N_, int G_) {
  int g = blockIdx.x*256 + threadIdx.x;
  if (g > G_) return;
  int lo = 0, hi = N_;
  while (lo < hi) { int m = (lo+hi) >> 1; if (batch[m] < g) lo = m+1; else hi = m; }
  gstart[g] = lo;
}

// ---------- xs[r][f] = bf16(dinv[r] * x[r][f]) ----------
__global__ void xs_k(const float* __restrict__ x, const float* __restrict__ dinv,
                     ushort* __restrict__ xs, int n4, int F_) {
  int i = blockIdx.x*256 + threadIdx.x;
  if (i >= n4) return;
  int row = (i << 2) / F_;
  float dv = dinv[row];
  float4 v = ((const float4*)x)[i];
  ushort4 o;
  o.x = f2b(v.x*dv); o.y = f2b(v.y*dv); o.z = f2b(v.z*dv); o.w = f2b(v.w*dv);
  ((ushort4*)xs)[i] = o;
}

// ---------- all three weight transposes in one kernel ----------
__global__ void wt3_k(const float* __restrict__ W0, const float* __restrict__ W1,
                      const float* __restrict__ W2, ushort* __restrict__ Wt0,
                      ushort* __restrict__ Wt1, ushort* __restrict__ Wt2,
                      int ksh0, int n0) {
  int idx = blockIdx.x*256 + threadIdx.x;
  if (idx < n0) {
    int n = idx >> ksh0, k = idx & ((1 << ksh0) - 1);
    Wt0[idx] = f2b(W0[(size_t)k*H + n]);
  } else if (idx < n0 + H*H) {
    int j = idx - n0;
    int n = j >> 8, k = j & 255;
    Wt1[j] = f2b(W1[(size_t)k*H + n]);
  } else if (idx < n0 + 2*H*H) {
    int j = idx - n0 - H*H;
    int n = j >> 8, k = j & 255;
    Wt2[j] = f2b(W2[(size_t)k*H + n]);
  }
}

// ---------- layer-0 aggregation on F channels: z = bf16(Â x) ----------
__global__ __launch_bounds__(1024) void aggregate0_k(
    const ushort* __restrict__ xs, const int* __restrict__ src,
    const int* __restrict__ rowptr, const float* __restrict__ dinv,
    ushort* __restrict__ z, int N_, int F_) {
  int t = threadIdx.x;
  int lane = t & 63, wv = t >> 6;
  int ch = lane * 2;
  for (int c = blockIdx.x*16 + wv; c < N_; c += gridDim.x*16) {
    float di = dinv[c];
    ushort2 sv = *(const ushort2*)(xs + (size_t)c*F_ + ch);
    float a0 = b2f(sv.x), b0 = b2f(sv.y);
    float a1=0.f,b1=0.f,a2=0.f,b2=0.f,a3=0.f,b3=0.f;
    int s = rowptr[c], e = rowptr[c+1];
    int j = s;
    for (; j + 8 <= e; j += 8) {
      int r0 = src[j],   r1 = src[j+1], r2 = src[j+2], r3 = src[j+3];
      int r4 = src[j+4], r5 = src[j+5], r6 = src[j+6], r7 = src[j+7];
      ushort2 v0 = *(const ushort2*)(xs + (size_t)r0*F_ + ch);
      ushort2 v1 = *(const ushort2*)(xs + (size_t)r1*F_ + ch);
      ushort2 v2 = *(const ushort2*)(xs + (size_t)r2*F_ + ch);
      ushort2 v3 = *(const ushort2*)(xs + (size_t)r3*F_ + ch);
      ushort2 v4 = *(const ushort2*)(xs + (size_t)r4*F_ + ch);
      ushort2 v5 = *(const ushort2*)(xs + (size_t)r5*F_ + ch);
      ushort2 v6 = *(const ushort2*)(xs + (size_t)r6*F_ + ch);
      ushort2 v7 = *(const ushort2*)(xs + (size_t)r7*F_ + ch);
      a0 += b2f(v0.x); b0 += b2f(v0.y);
      a1 += b2f(v1.x); b1 += b2f(v1.y);
      a2 += b2f(v2.x); b2 += b2f(v2.y);
      a3 += b2f(v3.x); b3 += b2f(v3.y);
      a0 += b2f(v4.x); b0 += b2f(v4.y);
      a1 += b2f(v5.x); b1 += b2f(v5.y);
      a2 += b2f(v6.x); b2 += b2f(v6.y);
      a3 += b2f(v7.x); b3 += b2f(v7.y);
    }
    for (; j + 4 <= e; j += 4) {
      int r0 = src[j], r1 = src[j+1], r2 = src[j+2], r3 = src[j+3];
      ushort2 v0 = *(const ushort2*)(xs + (size_t)r0*F_ + ch);
      ushort2 v1 = *(const ushort2*)(xs + (size_t)r1*F_ + ch);
      ushort2 v2 = *(const ushort2*)(xs + (size_t)r2*F_ + ch);
      ushort2 v3 = *(const ushort2*)(xs + (size_t)r3*F_ + ch);
      a0 += b2f(v0.x); b0 += b2f(v0.y);
      a1 += b2f(v1.x); b1 += b2f(v1.y);
      a2 += b2f(v2.x); b2 += b2f(v2.y);
      a3 += b2f(v3.x); b3 += b2f(v3.y);
    }
    for (; j < e; j++) {
      int r = src[j];
      ushort2 v = *(const ushort2*)(xs + (size_t)r*F_ + ch);
      a0 += b2f(v.x); b0 += b2f(v.y);
    }
    float sa = (a0+a1)+(a2+a3);
    float sb = (b0+b1)+(b2+b3);
    ushort2 o; o.x = f2b(sa*di); o.y = f2b(sb*di);
    *(ushort2*)(z + (size_t)c*F_ + ch) = o;
  }
}

// ---------- GEMM: 128-row x 256-col tile, 512 threads (8 waves) ----------
// K-independence of measured dur (layer0 K=128 == layers1/2 K=256 at ~77us)
// says per-block FIXED latency dominates; halving block count amortizes it.
// Wave w: row-half (w>>2)*64, col-slab (w&3)*64; per-wave body = R12's 64x64.
template<int K, int MODE, int FUSE, int RES>
__global__ __launch_bounds__(512) void gemm_mfma_k(
    const ushort* __restrict__ A, const ushort* __restrict__ Wt,
    const float* __restrict__ dinv, const float* __restrict__ bias,
    const float* __restrict__ stats, const float* __restrict__ g,
    const float* __restrict__ beta, ushort* __restrict__ hb,
    ushort* __restrict__ y, ushort* __restrict__ aggb_out,
    float* __restrict__ statsout, int N_, float invN) {
  __shared__ ushort At[128*256];
  __shared__ float scsh[2*H];
  __shared__ float ls[2*H];
  int t = threadIdx.x;
  int lane = t & 63, w = t >> 6;        // w in [0,8)
  int rblk = blockIdx.x * 128;
  int rh = (w >> 2) * 64;               // row-half within tile
  int c0 = (w & 3) * 64;
  int lr = lane & 15, lk = (lane >> 4) * 8;
  const int ROWB = K*2;

  if (FUSE) {
    if (t < H) {
      float mu  = stats[t]*invN;
      float var = stats[H+t]*invN - mu*mu;
      float sc  = g[t]*rsqrtf(var+EPS);
      scsh[t] = sc; scsh[H+t] = beta[t] - mu*sc;
    }
    __syncthreads();
  }
  constexpr int C4PR = K/4;
  constexpr int ITER = 128*C4PR/512;
#pragma unroll
  for (int it = 0; it < ITER; it++) {
    int idx = it*512 + t;
    int row = idx / C4PR;
    int c4 = (idx % C4PR) * 4;
    int grow = rblk + row;
    int gr = (grow < N_) ? grow : (N_-1);
    ushort4 av = *(const ushort4*)(A + (size_t)gr*K + c4);
    ushort4 o;
    if (FUSE) {
      float x0 = fmaxf(fmaf(b2f(av.x), scsh[c4+0], scsh[H+c4+0]), 0.f);
      float x1 = fmaxf(fmaf(b2f(av.y), scsh[c4+1], scsh[H+c4+1]), 0.f);
      float x2 = fmaxf(fmaf(b2f(av.z), scsh[c4+2], scsh[H+c4+2]), 0.f);
      float x3 = fmaxf(fmaf(b2f(av.w), scsh[c4+3], scsh[H+c4+3]), 0.f);
      if (RES) {
        ushort4 hv = *(const ushort4*)(hb + (size_t)gr*K + c4);
        x0 += b2f(hv.x); x1 += b2f(hv.y); x2 += b2f(hv.z); x3 += b2f(hv.w);
      }
      o.x = f2b(x0); o.y = f2b(x1); o.z = f2b(x2); o.w = f2b(x3);
      if (grow < N_) *(ushort4*)(hb + (size_t)grow*K + c4) = o;
    } else {
      o = av;
    }
    int byte = row*ROWB + ((c4*2) ^ ((row&7)<<4));
    *(ushort4*)((char*)At + byte) = o;
  }
  __syncthreads();

  f32x4 acc[4][4];
#pragma unroll
  for (int m = 0; m < 4; m++)
#pragma unroll
    for (int n = 0; n < 4; n++) acc[m][n] = (f32x4)0.f;

  const ushort* Wp[4];
#pragma unroll
  for (int n = 0; n < 4; n++) Wp[n] = Wt + (size_t)(c0 + n*16 + lr)*K + lk;

  const int NSTEP = K / 32;
  bf16x8 w0[4], w1[4], w2[4], a_cur[4], a_nxt[4];
#pragma unroll
  for (int n = 0; n < 4; n++) w0[n] = *(const bf16x8*)(Wp[n]);
#pragma unroll
  for (int n = 0; n < 4; n++) w1[n] = *(const bf16x8*)(Wp[n] + (NSTEP > 1 ? 32 : 0));
#pragma unroll
  for (int m = 0; m < 4; m++) {
    int row = rh + m*16 + lr;
    int byte = row*ROWB + ((lk*2) ^ ((row&7)<<4));
    a_cur[m] = *(const bf16x8*)((const char*)At + byte);
  }

#pragma unroll
  for (int s = 0; s < NSTEP; s++) {
    if (s + 2 < NSTEP) {
      int k0 = (s + 2) * 32;
#pragma unroll
      for (int n = 0; n < 4; n++) w2[n] = *(const bf16x8*)(Wp[n] + k0);
    }
    if (s + 1 < NSTEP) {
#pragma unroll
      for (int m = 0; m < 4; m++) {
        int row = rh + m*16 + lr;
        int byte = row*ROWB + ((((lk + (s+1)*32)*2)) ^ ((row&7)<<4));
        a_nxt[m] = *(const bf16x8*)((const char*)At + byte);
      }
    }
#pragma unroll
    for (int m = 0; m < 4; m++)
#pragma unroll
      for (int n = 0; n < 4; n++)
        acc[m][n] = __builtin_amdgcn_mfma_f32_16x16x32_bf16(a_cur[m], w0[n], acc[m][n], 0, 0, 0);
    if (s + 1 < NSTEP) {
#pragma unroll
      for (int n = 0; n < 4; n++) { w0[n] = w1[n]; }
#pragma unroll
      for (int m = 0; m < 4; m++) a_cur[m] = a_nxt[m];
    }
    if (s + 2 < NSTEP) {
#pragma unroll
      for (int n = 0; n < 4; n++) w1[n] = w2[n];
    }
  }

  int lrow = (lane >> 4) * 4;
  int lcol = lane & 15;

  if (MODE == 0) {
#pragma unroll
    for (int m = 0; m < 4; m++) {
#pragma unroll
      for (int r = 0; r < 4; r++) {
        int row = rblk + rh + m*16 + lrow + r;
        if (row < N_) {
          float dv = dinv[row];
#pragma unroll
          for (int n = 0; n < 4; n++)
            y[(size_t)row*H + c0 + n*16 + lcol] = f2b(acc[m][n][r] * dv);
        }
      }
    }
  } else {
    ls[t] = 0.f;                       // t in [0,512) == [0,2H)
    __syncthreads();
    float bvn[4];
#pragma unroll
    for (int n = 0; n < 4; n++) bvn[n] = bias[c0 + n*16 + lcol];
    float sn[4] = {0.f,0.f,0.f,0.f}, qn[4] = {0.f,0.f,0.f,0.f};
#pragma unroll
    for (int m = 0; m < 4; m++) {
#pragma unroll
      for (int r = 0; r < 4; r++) {
        int row = rblk + rh + m*16 + lrow + r;
        if (row < N_) {
#pragma unroll
          for (int n = 0; n < 4; n++) {
            float v = acc[m][n][r] + bvn[n];
            aggb_out[(size_t)row*H + c0 + n*16 + lcol] = f2b(v);
            sn[n] += v; qn[n] = fmaf(v, v, qn[n]);
          }
        }
      }
    }
#pragma unroll
    for (int n = 0; n < 4; n++) {
      atomicAdd(&ls[c0 + n*16 + lcol], sn[n]);
      atomicAdd(&ls[H + c0 + n*16 + lcol], qn[n]);
    }
    __syncthreads();
    atomicAdd(&statsout[t], ls[t]);
  }
}

// ---------- aggregation + fused BN stats (layers 1,2) — R12 1024-thread ----------
__global__ __launch_bounds__(1024) void aggregate_k(
    const ushort* __restrict__ y, const int* __restrict__ src,
    const int* __restrict__ rowptr, const float* __restrict__ dinv,
    const float* __restrict__ b, ushort* __restrict__ aggb,
    float* __restrict__ stats, int N_) {
  __shared__ float ls[2*H];
  int t = threadIdx.x;
  if (t < 2*H) ls[t] = 0.f;
  __syncthreads();

  int lane = t & 63, wv = t >> 6;
  int ch = lane * 4;
  float4 bv = *(const float4*)(b + ch);

  float s0=0.f, s1=0.f, s2=0.f, s3=0.f;
  float q0=0.f, q1=0.f, q2=0.f, q3=0.f;

  for (int c = blockIdx.x*16 + wv; c < N_; c += gridDim.x*16) {
    float di = dinv[c];
    ushort4 sv = *(const ushort4*)(y + (size_t)c*H + ch);
    float a0x = b2f(sv.x), a0y = b2f(sv.y), a0z = b2f(sv.z), a0w = b2f(sv.w);
    float a1x=0.f,a1y=0.f,a1z=0.f,a1w=0.f;
    float a2x=0.f,a2y=0.f,a2z=0.f,a2w=0.f;
    float a3x=0.f,a3y=0.f,a3z=0.f,a3w=0.f;
    int s = rowptr[c], e = rowptr[c+1];
    int j = s;
    for (; j + 8 <= e; j += 8) {
      int r0 = src[j],   r1 = src[j+1], r2 = src[j+2], r3 = src[j+3];
      int r4 = src[j+4], r5 = src[j+5], r6 = src[j+6], r7 = src[j+7];
      ushort4 v0 = *(const ushort4*)(y + (size_t)r0*H + ch);
      ushort4 v1 = *(const ushort4*)(y + (size_t)r1*H + ch);
      ushort4 v2 = *(const ushort4*)(y + (size_t)r2*H + ch);
      ushort4 v3 = *(const ushort4*)(y + (size_t)r3*H + ch);
      ushort4 v4 = *(const ushort4*)(y + (size_t)r4*H + ch);
      ushort4 v5 = *(const ushort4*)(y + (size_t)r5*H + ch);
      ushort4 v6 = *(const ushort4*)(y + (size_t)r6*H + ch);
      ushort4 v7 = *(const ushort4*)(y + (size_t)r7*H + ch);
      a0x += b2f(v0.x); a0y += b2f(v0.y); a0z += b2f(v0.z); a0w += b2f(v0.w);
      a1x += b2f(v1.x); a1y += b2f(v1.y); a1z += b2f(v1.z); a1w += b2f(v1.w);
      a2x += b2f(v2.x); a2y += b2f(v2.y); a2z += b2f(v2.z); a2w += b2f(v2.w);
      a3x += b2f(v3.x); a3y += b2f(v3.y); a3z += b2f(v3.z); a3w += b2f(v3.w);
      a0x += b2f(v4.x); a0y += b2f(v4.y); a0z += b2f(v4.z); a0w += b2f(v4.w);
      a1x += b2f(v5.x); a1y += b2f(v5.y); a1z += b2f(v5.z); a1w += b2f(v5.w);
      a2x += b2f(v6.x); a2y += b2f(v6.y); a2z += b2f(v6.z); a2w += b2f(v6.w);
      a3x += b2f(v7.x); a3y += b2f(v7.y); a3z += b2f(v7.z); a3w += b2f(v7.w);
    }
    for (; j + 4 <= e; j += 4) {
      int r0 = src[j], r1 = src[j+1], r2 = src[j+2], r3 = src[j+3];
      ushort4 v0 = *(const ushort4*)(y + (size_t)r0*H + ch);
      ushort4 v1 = *(const ushort4*)(y + (size_t)r1*H + ch);
      ushort4 v2 = *(const ushort4*)(y + (size_t)r2*H + ch);
      ushort4 v3 = *(const ushort4*)(y + (size_t)r3*H + ch);
      a0x += b2f(v0.x); a0y += b2f(v0.y); a0z += b2f(v0.z); a0w += b2f(v0.w);
      a1x += b2f(v1.x); a1y += b2f(v1.y); a1z += b2f(v1.z); a1w += b2f(v1.w);
      a2x += b2f(v2.x); a2y += b2f(v2.y); a2z += b2f(v2.z); a2w += b2f(v2.w);
      a3x += b2f(v3.x); a3y += b2f(v3.y); a3z += b2f(v3.z); a3w += b2f(v3.w);
    }
    for (; j < e; j++) {
      int r = src[j];
      ushort4 v = *(const ushort4*)(y + (size_t)r*H + ch);
      a0x += b2f(v.x); a0y += b2f(v.y); a0z += b2f(v.z); a0w += b2f(v.w);
    }
    float ax = (a0x + a1x) + (a2x + a3x);
    float ay = (a0y + a1y) + (a2y + a3y);
    float az = (a0z + a1z) + (a2z + a3z);
    float aw = (a0w + a1w) + (a2w + a3w);
    float ox = fmaf(ax, di, bv.x);
    float oy = fmaf(ay, di, bv.y);
    float oz = fmaf(az, di, bv.z);
    float ow = fmaf(aw, di, bv.w);
    ushort4 ob; ob.x = f2b(ox); ob.y = f2b(oy); ob.z = f2b(oz); ob.w = f2b(ow);
    *(ushort4*)(aggb + (size_t)c*H + ch) = ob;
    s0 += ox; q0 = fmaf(ox, ox, q0);
    s1 += oy; q1 = fmaf(oy, oy, q1);
    s2 += oz; q2 = fmaf(oz, oz, q2);
    s3 += ow; q3 = fmaf(ow, ow, q3);
  }

  atomicAdd(&ls[ch+0], s0); atomicAdd(&ls[H+ch+0], q0);
  atomicAdd(&ls[ch+1], s1); atomicAdd(&ls[H+ch+1], q1);
  atomicAdd(&ls[ch+2], s2); atomicAdd(&ls[H+ch+2], q2);
  atomicAdd(&ls[ch+3], s3); atomicAdd(&ls[H+ch+3], q3);
  __syncthreads();
  if (t < 2*H) atomicAdd(&stats[t], ls[t]);
}

// ---------- fused BN(layer2) + pooling + MLP (empty graphs skip k-loop) ----------
__global__ __launch_bounds__(256) void pool_mlp_k(
    const ushort* __restrict__ hb, const ushort* __restrict__ aggb,
    const float* __restrict__ stats, const float* __restrict__ g2,
    const float* __restrict__ be2, const int* __restrict__ gstart,
    const float* __restrict__ mW1, const float* __restrict__ mb1,
    const float* __restrict__ mW2, const float* __restrict__ mb2,
    float* __restrict__ out, float invN) {
  int g = blockIdx.x, t = threadIdx.x; // 256 threads, t = channel
  __shared__ float p[H];
  __shared__ float mid[128];
  int s = gstart[g], e = gstart[g+1];
  int nonempty = (e > s);
  if (nonempty) {
    float mu  = stats[t]*invN;
    float var = stats[H+t]*invN - mu*mu;
    float sc  = g2[t]*rsqrtf(var+EPS);
    float sh  = be2[t] - mu*sc;
    float sum = 0.f;
    for (int n = s; n < e; n++) {
      float av = b2f(aggb[(size_t)n*H + t]);
      float hv = b2f(hb[(size_t)n*H + t]);
      sum += fmaxf(fmaf(av, sc, sh), 0.f) + hv;
    }
    float cnt = (float)(e - s);
    p[t] = sum/cnt + sum;
  }
  __syncthreads();
  if (t < 128) {
    float a = mb1[t];
    if (nonempty) {
      for (int k = 0; k < H; k++) a = fmaf(p[k], mW1[(size_t)k*128 + t], a);
    }
    a = fmaxf(a, 0.f);
    mid[t] = a * mW2[t];
  }
  __syncthreads();
  for (int off = 64; off > 0; off >>= 1) {
    if (t < off) mid[t] += mid[t+off];
    __syncthreads();
  }
  if (t == 0) out[g] = mid[0] + mb2[0];
}

extern "C" void kernel_launch(void* const* d_in, const int* in_sizes, int n_in,
                              void* d_out, int out_size, void* d_ws, size_t ws_size,
                              hipStream_t stream) {
  const float* x        = (const float*)d_in[0];
  const void*  ei_raw   = d_in[1];
  const void*  batch_raw= d_in[2];
  const float* W0 = (const float*)d_in[3];
  const float* b0 = (const float*)d_in[4];
  const float* g0 = (const float*)d_in[5];
  const float* be0= (const float*)d_in[6];
  const float* W1 = (const float*)d_in[7];
  const float* b1 = (const float*)d_in[8];
  const float* g1 = (const float*)d_in[9];
  const float* be1= (const float*)d_in[10];
  const float* W2 = (const float*)d_in[11];
  const float* b2 = (const float*)d_in[12];
  const float* g2 = (const float*)d_in[13];
  const float* be2= (const float*)d_in[14];
  const float* mW1= (const float*)d_in[15];
  const float* mb1= (const float*)d_in[16];
  const float* mW2= (const float*)d_in[17];
  const float* mb2= (const float*)d_in[18];
  float* out = (float*)d_out;

  int N_ = in_sizes[2];
  int E_ = in_sizes[1] / 2;
  int F_ = in_sizes[0] / N_;
  int G_ = out_size;

  char* ws = (char*)d_ws;
  size_t off = 0;
  auto alloc = [&](size_t bytes) -> void* {
    void* p = ws + off;
    off = (off + bytes + 255) & ~(size_t)255;
    return p;
  };
  ushort* aggb   = (ushort*)alloc((size_t)N_*H*2);
  ushort* y      = (ushort*)alloc((size_t)N_*H*2);
  ushort* hb     = (ushort*)alloc((size_t)N_*H*2);
  ushort* xs     = (ushort*)alloc((size_t)N_*F_*2);
  ushort* z      = (ushort*)alloc((size_t)N_*F_*2);
  ushort* Wt0    = (ushort*)alloc((size_t)F_*H*2);
  ushort* Wt1    = (ushort*)alloc((size_t)H*H*2);
  ushort* Wt2    = (ushort*)alloc((size_t)H*H*2);
  int*    eidx   = (int*)   alloc((size_t)2*E_*4);
  int*    csr    = (int*)   alloc((size_t)E_*4);
  int*    batch  = (int*)   alloc((size_t)N_*4);
  int*    cnt    = (int*)   alloc((size_t)N_*4);
  int*    fill   = (int*)   alloc((size_t)N_*4);
  int*    rowptr = (int*)   alloc((size_t)(N_+1)*4);
  int*    bsum   = (int*)   alloc((size_t)((N_+1023)/1024 + 64)*4);
  float*  dinv   = (float*) alloc((size_t)N_*4);
  float*  stats  = (float*) alloc(6*H*4);   // stats0 | stats1 | stats2
  int*    gstart = (int*)   alloc((size_t)(G_+1)*4);
  int*    flag   = (int*)   alloc(4);
  float*  stats0 = stats;
  float*  stats1 = stats + 2*H;
  float*  stats2 = stats + 4*H;

  // index preprocessing (degree count fused into edge-index convert)
  detect_i64_k<<<1, 64, 0, stream>>>((const int*)ei_raw, flag);
  hipMemsetAsync(cnt, 0, (size_t)N_*4, stream);
  hipMemsetAsync(fill, 0, (size_t)N_*4, stream);
  hipMemsetAsync(stats, 0, 6*H*4, stream);
  convert_idx_k<<<(2*E_+255)/256, 256, 0, stream>>>(ei_raw, flag, eidx, 2*E_, cnt, E_);
  convert_idx_k<<<(N_+255)/256, 256, 0, stream>>>(batch_raw, flag, batch, N_, nullptr, 0);
  int nb1 = (N_ + 1023) / 1024;
  scan1_k<<<nb1, 256, 0, stream>>>(cnt, rowptr, bsum, dinv, N_);
  scan2_k<<<1, 64, 0, stream>>>(bsum, rowptr, nb1, N_);
  scan3_k<<<nb1, 256, 0, stream>>>(rowptr, bsum, N_);
  fill_csr_k<<<(E_+255)/256, 256, 0, stream>>>(eidx, eidx + E_, rowptr, fill, csr, E_);
  graph_starts_k<<<(G_+256)/256, 256, 0, stream>>>(batch, gstart, N_, G_);

  // converts
  int ksh0 = 31 - __builtin_clz(F_);
  xs_k<<<((N_*F_/4)+255)/256, 256, 0, stream>>>(x, dinv, xs, N_*F_/4, F_);
  int wtot = F_*H + 2*H*H;
  wt3_k<<<(wtot+255)/256, 256, 0, stream>>>(W0, W1, W2, Wt0, Wt1, Wt2, ksh0, F_*H);

  float invN = 1.0f / (float)N_;
  int nb = (N_ + 127) / 128;

  // ---- layer 0: aggregate0 -> GEMM(z,W0)+bias+stats0 ----
  aggregate0_k<<<512, 1024, 0, stream>>>(xs, csr, rowptr, dinv, z, N_, F_);
  if (F_ == 128)
    gemm_mfma_k<128,1,0,0><<<nb, 512, 0, stream>>>(z, Wt0, dinv, b0, nullptr, nullptr,
        nullptr, nullptr, y, aggb, stats0, N_, invN);
  else
    gemm_mfma_k<256,1,0,0><<<nb, 512, 0, stream>>>(z, Wt0, dinv, b0, nullptr, nullptr,
        nullptr, nullptr, y, aggb, stats0, N_, invN);

  // ---- layer 1: GEMM(h0=relu(bn0(aggb)),W1) fused -> aggregate+stats1 ----
  gemm_mfma_k<256,0,1,0><<<nb, 512, 0, stream>>>(aggb, Wt1, dinv, b1, stats0, g0,
      be0, hb, y, nullptr, nullptr, N_, invN);
  aggregate_k<<<512, 1024, 0, stream>>>(y, csr, rowptr, dinv, b1, aggb, stats1, N_);

  // ---- layer 2: GEMM(h1=h0+relu(bn1(aggb)),W2) fused -> aggregate+stats2 ----
  gemm_mfma_k<256,0,1,1><<<nb, 512, 0, stream>>>(aggb, Wt2, dinv, b2, stats1, g1,
      be1, hb, y, nullptr, nullptr, N_, invN);
  aggregate_k<<<512, 1024, 0, stream>>>(y, csr, rowptr, dinv, b2, aggb, stats2, N_);

  // ---- fused bn2 + pool + MLP (all graphs; empty ones skip the k-loop) ----
  pool_mlp_k<<<G_, 256, 0, stream>>>(hb, aggb, stats2, g2, be2, gstart,
      mW1, mb1, mW2, mb2, out, invN);
}